// Round 1
// baseline (412.133 us; speedup 1.0000x reference)
//
#include <hip/hip_runtime.h>
#include <hip/hip_bf16.h>

// out[i,j] = 2*x[i,j] + 5 - (i+j), x: 8192x8192 fp32.
// Memory-bound elementwise: 256 MiB read + 256 MiB write. Target HBM ceiling.
// One thread per float4 (16 B/lane coalesced). i = idx>>13, j = idx&8191
// (N = M = 8192, pow2 -> shift/mask only).

#define N_ROWS 8192
#define N_COLS 8192
#define LOG2_COLS 13

__global__ __launch_bounds__(256) void affine_elemwise_kernel(
    const float* __restrict__ x, float* __restrict__ out) {
    // Each thread handles 4 consecutive elements (same row: 8192 % 4 == 0).
    const long long t = (long long)blockIdx.x * blockDim.x + threadIdx.x;
    const long long e = t * 4;                 // flat element base index
    const int i = (int)(e >> LOG2_COLS);       // row
    const int j = (int)(e & (N_COLS - 1));     // col base

    const float4 v = *reinterpret_cast<const float4*>(x + e);

    // c = 5 - (i + j) for the first component; each next col subtracts 1 more.
    const float c = 5.0f - (float)(i + j);

    float4 r;
    r.x = fmaf(2.0f, v.x, c);
    r.y = fmaf(2.0f, v.y, c - 1.0f);
    r.z = fmaf(2.0f, v.z, c - 2.0f);
    r.w = fmaf(2.0f, v.w, c - 3.0f);

    *reinterpret_cast<float4*>(out + e) = r;
}

extern "C" void kernel_launch(void* const* d_in, const int* in_sizes, int n_in,
                              void* d_out, int out_size, void* d_ws, size_t ws_size,
                              hipStream_t stream) {
    const float* x = (const float*)d_in[0];
    float* out = (float*)d_out;

    // 8192*8192 / 4 elems per thread / 256 threads per block = 65536 blocks
    const int threads = 256;
    const long long total_vec4 = (long long)N_ROWS * N_COLS / 4;
    const int blocks = (int)(total_vec4 / threads);

    affine_elemwise_kernel<<<blocks, threads, 0, stream>>>(x, out);
}